// Round 13
// baseline (932.712 us; speedup 1.0000x reference)
//
#include <hip/hip_runtime.h>
#include <hip/hip_bf16.h>

#define BB 128
#define SS 1024
#define HH 128
#define G3 384
#define NT (BB * SS)   // 131072 tokens

typedef __hip_bfloat16 bf16;
typedef unsigned int uint;
typedef unsigned short ushort;
typedef _Float16 f16;
typedef f16 f16x2 __attribute__((ext_vector_type(2)));
typedef f16 f16x8 __attribute__((ext_vector_type(8)));
typedef float f32x4 __attribute__((ext_vector_type(4)));

__device__ __forceinline__ float leaky(float x) { return x >= 0.f ? x : 0.01f * x; }
__device__ __forceinline__ f16x2 u2h(uint u) { return __builtin_bit_cast(f16x2, u); }
__device__ __forceinline__ uint packh2(float a, float b) {
  f16x2 h; h.x = (f16)a; h.y = (f16)b;
  return __builtin_bit_cast(uint, h);
}
__device__ __forceinline__ uint h1(float a) {
  return (uint)__builtin_bit_cast(ushort, (f16)a);
}
__device__ __forceinline__ uint bf_rne(float f) {
  uint u = __float_as_uint(f);
  return (u + 0x7FFFu + ((u >> 16) & 1u)) >> 16;
}
__device__ __forceinline__ float shflx(float v, int m) { return __shfl_xor(v, m, 64); }
// quad_perm DPP: xor1 = [1,0,3,2] (0xB1), xor2 = [2,3,0,1] (0x4E)
__device__ __forceinline__ float dpp_xor1(float v) {
  int i = __builtin_bit_cast(int, v);
  i = __builtin_amdgcn_update_dpp(0, i, 0xB1, 0xF, 0xF, true);
  return __builtin_bit_cast(float, i);
}
__device__ __forceinline__ float dpp_xor2(float v) {
  int i = __builtin_bit_cast(int, v);
  i = __builtin_amdgcn_update_dpp(0, i, 0x4E, 0xF, 0xF, true);
  return __builtin_bit_cast(float, i);
}
__device__ __forceinline__ uint dpp_xor1_u(uint v) {
  int i = __builtin_amdgcn_update_dpp(0, (int)v, 0xB1, 0xF, 0xF, true);
  return (uint)i;
}
#define WSYNC() asm volatile("s_waitcnt lgkmcnt(0)" ::: "memory")

template <int NP>
__device__ __forceinline__ void ldrow(const float* __restrict__ p, f16x2* w) {
#pragma unroll
  for (int i = 0; i < NP; ++i) {
    f16x2 h; h.x = (f16)p[2 * i]; h.y = (f16)p[2 * i + 1];
    w[i] = h;
  }
}
__device__ __forceinline__ f16x8 ldw8(const float* __restrict__ p) {
  f16x8 v;
#pragma unroll
  for (int j = 0; j < 8; ++j) v[j] = (f16)p[j];
  return v;
}
template <int NP>
__device__ __forceinline__ float dot2l(const uint* __restrict__ x,
                                       const f16x2* __restrict__ w, float acc) {
#pragma unroll
  for (int i = 0; i < NP / 4; ++i) {
    uint4 uu = ((const uint4*)x)[i];
    acc = __builtin_amdgcn_fdot2(u2h(uu.x), w[4 * i + 0], acc, false);
    acc = __builtin_amdgcn_fdot2(u2h(uu.y), w[4 * i + 1], acc, false);
    acc = __builtin_amdgcn_fdot2(u2h(uu.z), w[4 * i + 2], acc, false);
    acc = __builtin_amdgcn_fdot2(u2h(uu.w), w[4 * i + 3], acc, false);
  }
  return acc;
}
// 4 packed pairs (x) vs 4 packed pairs (w)
__device__ __forceinline__ float d4(uint4 x, uint4 w, float acc) {
  acc = __builtin_amdgcn_fdot2(u2h(x.x), u2h(w.x), acc, false);
  acc = __builtin_amdgcn_fdot2(u2h(x.y), u2h(w.y), acc, false);
  acc = __builtin_amdgcn_fdot2(u2h(x.z), u2h(w.z), acc, false);
  acc = __builtin_amdgcn_fdot2(u2h(x.w), u2h(w.w), acc, false);
  return acc;
}

// ---------------- pre_a: encoders + attention + LN -> xnh (f16 pairs) -------
__global__ __launch_bounds__(256, 4) void pre_a(
    const float* __restrict__ obs, const float* __restrict__ me_w1,
    const float* __restrict__ me_b1, const float* __restrict__ me_w2,
    const float* __restrict__ me_b2, const float* __restrict__ ae_w1,
    const float* __restrict__ ae_b1, const float* __restrict__ ae_w2,
    const float* __restrict__ ae_b2, const float* __restrict__ ipw,
    const float* __restrict__ ipb, const float* __restrict__ opw,
    const float* __restrict__ opb, const float* __restrict__ lng,
    const float* __restrict__ lnb, uint* __restrict__ xnh) {
  __shared__ float ss[352];
  __shared__ __align__(16) uint4 w4[8 * 256];  // 32 KB: [chunk c][row r]
  __shared__ __align__(16) uint ex[4][176];

  const int tid = threadIdx.x;
  const int wid = tid >> 6, l = tid & 63;
  if (tid < 96) ss[tid] = me_w1[tid];
  if (tid < 32) ss[96 + tid] = me_b1[tid];
  if (tid < 192) ss[128 + tid] = ae_w1[tid];
  if (tid < 32) ss[320 + tid] = ae_b1[tid];

  for (int idx = tid; idx < 2048; idx += 256) {
    const int r = idx & 255, c = idx >> 8;
    const float* src =
        (r < 192 ? ipw + (size_t)r * 64 : opw + (size_t)(r - 192) * 64) + c * 8;
    uint4 u;
    u.x = packh2(src[0], src[1]);
    u.y = packh2(src[2], src[3]);
    u.z = packh2(src[4], src[5]);
    u.w = packh2(src[6], src[7]);
    w4[(c << 8) + r] = u;
  }

  f16x2 wme2[16], wae2[16];
  ldrow<16>(me_w2 + l * 32, wme2);
  ldrow<16>(ae_w2 + l * 32, wae2);
  const float bme2 = me_b2[l], bae2 = ae_b2[l];
  const float bq = ipb[l], bk = ipb[64 + l], bv = ipb[128 + l], bop = opb[l];
  const float gl = lng[l], bl = lnb[l];
  __syncthreads();

  uint* um = ex[wid];
  uint* ua = um + 32;
  uint* e1 = um + 48;
  uint* e2 = um + 80;
  uint* ea = um + 112;
  uint* ec = um + 144;

  for (int base = blockIdx.x * 4; base < NT; base += 4096) {
    const size_t token = base + wid;
    const float4* ob4 = (const float4*)(obs + token * 12);
    float4 o0 = ob4[0], o1 = ob4[1], o2 = ob4[2];

    const int row = l & 31;
    const bool m2h = l >= 32;
    float i0 = m2h ? o0.w : o0.x, i1 = m2h ? o1.x : o0.y, i2 = m2h ? o1.y : o0.z;
    float t1 = ss[96 + row] + i0 * ss[row * 3] + i1 * ss[row * 3 + 1] + i2 * ss[row * 3 + 2];
    t1 = leaky(t1);
    float ta = ss[320 + row] + o1.z * ss[128 + row * 6] + o1.w * ss[128 + row * 6 + 1] +
               o2.x * ss[128 + row * 6 + 2] + o2.y * ss[128 + row * 6 + 3] +
               o2.z * ss[128 + row * 6 + 4] + o2.w * ss[128 + row * 6 + 5];
    ta = leaky(ta);
    float t1p = shflx(t1, 1), tap = shflx(ta, 1);
    if (!(l & 1)) {
      um[l >> 1] = packh2(t1, t1p);
      if (l < 32) ua[l >> 1] = packh2(ta, tap);
    }
    WSYNC();

    float m1e = dot2l<16>(um, wme2, bme2);
    float m2e = dot2l<16>(um + 16, wme2, bme2);
    float ace = dot2l<16>(ua, wae2, bae2);
    float m1p = shflx(m1e, 1), m2p = shflx(m2e, 1), acp = shflx(ace, 1);
    if (!(l & 1)) {
      e1[l >> 1] = packh2(m1e, m1p);
      e2[l >> 1] = packh2(m2e, m2p);
      ea[l >> 1] = packh2(ace, acp);
    }
    WSYNC();

    float q = bq, k1 = bk, k2 = bk, v1 = bv, v2 = bv;
    {
      const uint4* xe1 = (const uint4*)e1;
      const uint4* xe2 = (const uint4*)e2;
      const uint4* xea = (const uint4*)ea;
#pragma unroll
      for (int c = 0; c < 8; ++c) {
        uint4 x1 = xe1[c], x2 = xe2[c], xa = xea[c];
        uint4 uq = w4[(c << 8) + l];
        uint4 uk = w4[(c << 8) + 64 + l];
        uint4 uv = w4[(c << 8) + 128 + l];
        q = d4(xa, uq, q);
        k1 = d4(x1, uk, k1);
        k2 = d4(x2, uk, k2);
        v1 = d4(x1, uv, v1);
        v2 = d4(x2, uv, v2);
      }
    }

    float p1 = q * k1, p2 = q * k2;
    p1 += shflx(p1, 1); p2 += shflx(p2, 1);
    p1 += shflx(p1, 2); p2 += shflx(p2, 2);
    p1 += shflx(p1, 4); p2 += shflx(p2, 4);
    p1 += shflx(p1, 8); p2 += shflx(p2, 8);
    float s1 = p1 * 0.25f, s2 = p2 * 0.25f;
    float mx = fmaxf(s1, s2);
    float ev1 = __expf(s1 - mx), ev2 = __expf(s2 - mx);
    float a1 = ev1 / (ev1 + ev2);
    float ctx = a1 * v1 + (1.f - a1) * v2;
    float cxp = shflx(ctx, 1);
    if (!(l & 1)) ec[l >> 1] = packh2(ctx, cxp);
    WSYNC();

    float ao = bop;
    {
      const uint4* xec = (const uint4*)ec;
#pragma unroll
      for (int c = 0; c < 8; ++c) {
        ao = d4(xec[c], w4[(c << 8) + 192 + l], ao);
      }
    }
    float x = ao + ace;
    float s = x, s2s = x * x;
#pragma unroll
    for (int off = 32; off; off >>= 1) {
      s += shflx(s, off);
      s2s += shflx(s2s, off);
    }
    float mu = s * (1.f / 64.f);
    float var = s2s * (1.f / 64.f) - mu * mu;
    float rs = rsqrtf(var + 1e-5f);
    float xn = (x - mu) * rs * gl + bl;
    float xnp = shflx(xn, 1);
    if (!(l & 1)) xnh[token * 32 + (l >> 1)] = packh2(xn, xnp);
  }
}

// ---------------- pre_b (MFMA): xp[NT,384] = xn[NT,64] @ W_ih^T + b ---------
__global__ __launch_bounds__(256) void pre_b(const uint* __restrict__ xnh,
                                             const float* __restrict__ wih,
                                             const float* __restrict__ bih,
                                             uint* __restrict__ xp32) {
  const int tid = threadIdx.x;
  const int l = tid & 63, wv = tid >> 6;
  const int n16 = l & 15, q = l >> 4;

  f16x8 Bf[6][2];
  float bias_l[6];
#pragma unroll
  for (int i = 0; i < 6; ++i) {
    const int n = (wv * 6 + i) * 16 + n16;
    const float* wrow = wih + (size_t)n * 64;
    Bf[i][0] = ldw8(wrow + q * 8);
    Bf[i][1] = ldw8(wrow + 32 + q * 8);
    bias_l[i] = bih[n];
  }

  for (int tile = blockIdx.x; tile < NT / 16; tile += gridDim.x) {
    const uint4* arow = (const uint4*)(xnh + (size_t)(tile * 16 + n16) * 32);
    f16x8 A0 = __builtin_bit_cast(f16x8, arow[q]);
    f16x8 A1 = __builtin_bit_cast(f16x8, arow[4 + q]);
#pragma unroll
    for (int i = 0; i < 6; ++i) {
      const int nt = wv * 6 + i;
      f32x4 acc = {0.f, 0.f, 0.f, 0.f};
      acc = __builtin_amdgcn_mfma_f32_16x16x32_f16(A0, Bf[i][0], acc, 0, 0, 0);
      acc = __builtin_amdgcn_mfma_f32_16x16x32_f16(A1, Bf[i][1], acc, 0, 0, 0);
#pragma unroll
      for (int r = 0; r < 4; ++r) {
        uint bv = bf_rne(acc[r] + bias_l[i]);
        uint pv = dpp_xor1_u(bv);
        if (!(l & 1))
          xp32[(size_t)(tile * 16 + q * 4 + r) * 192 + nt * 8 + (n16 >> 1)] =
              bv | (pv << 16);
      }
    }
  }
}

// ---------------- gru: quad split-k=4 + 2-hop DPP combine, 1 barrier/step ---
// 576 threads: waves 0-7 compute. Lane quad (par=lane&3) splits k=128 into 4;
// output j = wv*16 + (lane>>2); 48 fdot2/lane, chain depth 16; partials
// combined with quad_perm xor1+xor2; gates redundant across the quad; par==0
// publishes. Wave 8 = producer ring (unchanged). 1 lgkm-only barrier/step.
__global__ __launch_bounds__(576, 1) void gru_kernel(
    const bf16* __restrict__ xp, const float* __restrict__ hs,
    const float* __restrict__ whh, const float* __restrict__ bhh,
    ushort* __restrict__ gouth, float* __restrict__ hlast) {
  __shared__ __align__(16) uint hbuf[2][64];
  __shared__ __align__(16) uint ring[8 * 192];
  const int tid = threadIdx.x;
  const int b = blockIdx.x;
  const bool comp = tid < 512;
  const int lane = tid & 63;
  const int wv_ = tid >> 6;
  const int par = lane & 3;            // k-quarter
  const int j = (wv_ << 4) + (lane >> 2);  // output 0..127 (waves 0-7)
  const int pid = tid - 512;           // producer lane 0..63

  f16x2 wr[16], wz[16], wg[16];
  float br = 0.f, bz = 0.f, bg = 0.f, hprev = 0.f;
  const uint* xr32 = (const uint*)(xp + (size_t)b * SS * G3);
  uint a0 = 0, a1 = 0, a2 = 0, c0 = 0, c1 = 0, c2 = 0;
  if (comp) {
    ldrow<16>(whh + (size_t)j * HH + par * 32, wr);
    ldrow<16>(whh + (size_t)(HH + j) * HH + par * 32, wz);
    ldrow<16>(whh + (size_t)(2 * HH + j) * HH + par * 32, wg);
    br = bhh[j]; bz = bhh[HH + j]; bg = bhh[2 * HH + j];
    hprev = hs[b * HH + j];
    if (tid < 64) hbuf[0][tid] = packh2(hs[b * HH + 2 * tid], hs[b * HH + 2 * tid + 1]);
  } else {
    for (int s = 0; s < 4; ++s) {
      const uint* p = xr32 + s * 192 + pid * 3;
      uint v0 = p[0], v1 = p[1], v2 = p[2];
      uint* qq = ring + s * 192 + pid * 3;
      qq[0] = v0; qq[1] = v1; qq[2] = v2;
    }
    const uint* pa = xr32 + 4 * 192 + pid * 3;
    a0 = pa[0]; a1 = pa[1]; a2 = pa[2];
    const uint* pb = xr32 + 5 * 192 + pid * 3;
    c0 = pb[0]; c1 = pb[1]; c2 = pb[2];
  }
  __syncthreads();

  const ushort* ring_us = (const ushort*)ring;
  ushort* grow = gouth + (size_t)b * SS * HH;

#define CSTEP(TT, RD, WRI)                                                     \
  {                                                                            \
    const int slot = (TT) & 7;                                                 \
    uint bxr = ring_us[slot * 384 + j];                                        \
    uint bxz = ring_us[slot * 384 + 128 + j];                                  \
    uint bxg = ring_us[slot * 384 + 256 + j];                                  \
    const uint4* hb4 = (const uint4*)(hbuf[RD] + par * 16);                    \
    float ar = 0.f, az = 0.f, ag = 0.f;                                        \
    _Pragma("unroll") for (int i = 0; i < 4; ++i) {                            \
      uint4 hh = hb4[i];                                                       \
      f16x2 h0 = u2h(hh.x), hA = u2h(hh.y), h2 = u2h(hh.z), h3 = u2h(hh.w);    \
      ar = __builtin_amdgcn_fdot2(h0, wr[4 * i + 0], ar, false);               \
      az = __builtin_amdgcn_fdot2(h0, wz[4 * i + 0], az, false);               \
      ag = __builtin_amdgcn_fdot2(h0, wg[4 * i + 0], ag, false);               \
      ar = __builtin_amdgcn_fdot2(hA, wr[4 * i + 1], ar, false);               \
      az = __builtin_amdgcn_fdot2(hA, wz[4 * i + 1], az, false);               \
      ag = __builtin_amdgcn_fdot2(hA, wg[4 * i + 1], ag, false);               \
      ar = __builtin_amdgcn_fdot2(h2, wr[4 * i + 2], ar, false);               \
      az = __builtin_amdgcn_fdot2(h2, wz[4 * i + 2], az, false);               \
      ag = __builtin_amdgcn_fdot2(h2, wg[4 * i + 2], ag, false);               \
      ar = __builtin_amdgcn_fdot2(h3, wr[4 * i + 3], ar, false);               \
      az = __builtin_amdgcn_fdot2(h3, wz[4 * i + 3], az, false);               \
      ag = __builtin_amdgcn_fdot2(h3, wg[4 * i + 3], ag, false);               \
    }                                                                          \
    ar += dpp_xor1(ar); az += dpp_xor1(az); ag += dpp_xor1(ag);                \
    ar += dpp_xor2(ar); az += dpp_xor2(az); ag += dpp_xor2(ag);                \
    float xrf = __uint_as_float(bxr << 16);                                    \
    float xzf = __uint_as_float(bxz << 16);                                    \
    float xgf = __uint_as_float(bxg << 16);                                    \
    float r = 1.f / (1.f + __expf(-(xrf + ar + br)));                          \
    float z = 1.f / (1.f + __expf(-(xzf + az + bz)));                          \
    float gp = xgf + r * (ag + bg);                                            \
    float e = __expf(-2.f * fabsf(gp));                                        \
    float th = copysignf((1.f - e) / (1.f + e), gp);                           \
    float hn = (1.f - z) * th + z * hprev;                                     \
    hprev = hn;                                                                \
    if (!par) {                                                                \
      ((ushort*)hbuf[WRI])[j] = (ushort)h1(hn);                                \
      grow[(size_t)(TT)*HH + j] = (ushort)h1(hn);                              \
    }                                                                          \
  }

#define PSTEP(TT, R0, R1, R2)                                                  \
  {                                                                            \
    const int wrow = (TT) + 4;                                                 \
    if (wrow < SS) {                                                           \
      uint* qq = ring + (wrow & 7) * 192 + pid * 3;                            \
      qq[0] = R0; qq[1] = R1; qq[2] = R2;                                      \
      const int lrow = (TT) + 6;                                               \
      if (lrow < SS) {                                                         \
        const uint* p = xr32 + lrow * 192 + pid * 3;                           \
        R0 = p[0]; R1 = p[1]; R2 = p[2];                                       \
      }                                                                        \
    }                                                                          \
  }

  for (int t = 0; t < SS; t += 2) {
    if (comp) {
      CSTEP(t, 0, 1);
    } else {
      PSTEP(t, a0, a1, a2);
    }
    asm volatile("s_waitcnt lgkmcnt(0)\n\ts_barrier" ::: "memory");
    if (comp) {
      CSTEP(t + 1, 1, 0);
    } else {
      PSTEP(t + 1, c0, c1, c2);
    }
    asm volatile("s_waitcnt lgkmcnt(0)\n\ts_barrier" ::: "memory");
  }
#undef CSTEP
#undef PSTEP
  if (comp && !par) hlast[b * HH + j] = hprev;
}

// ---------------- mlp0 (MFMA): f0[NT,128] = leaky(g @ w0^T + b0) ------------
__global__ __launch_bounds__(256) void mlp0(const uint* __restrict__ gh,
                                            const float* __restrict__ w0,
                                            const float* __restrict__ b0,
                                            uint* __restrict__ f0h32) {
  const int tid = threadIdx.x;
  const int l = tid & 63, wv = tid >> 6;
  const int n16 = l & 15, q = l >> 4;

  f16x8 Bf[2][4];
  float bias_l[2];
#pragma unroll
  for (int i = 0; i < 2; ++i) {
    const int n = (wv * 2 + i) * 16 + n16;
    const float* wrow = w0 + (size_t)n * 128;
#pragma unroll
    for (int f = 0; f < 4; ++f) Bf[i][f] = ldw8(wrow + f * 32 + q * 8);
    bias_l[i] = b0[n];
  }

  for (int tile = blockIdx.x; tile < NT / 16; tile += gridDim.x) {
    const uint4* arow = (const uint4*)(gh + (size_t)(tile * 16 + n16) * 64);
    f16x8 A[4];
#pragma unroll
    for (int f = 0; f < 4; ++f) A[f] = __builtin_bit_cast(f16x8, arow[f * 4 + q]);
#pragma unroll
    for (int i = 0; i < 2; ++i) {
      const int nt = wv * 2 + i;
      f32x4 acc = {0.f, 0.f, 0.f, 0.f};
#pragma unroll
      for (int f = 0; f < 4; ++f)
        acc = __builtin_amdgcn_mfma_f32_16x16x32_f16(A[f], Bf[i][f], acc, 0, 0, 0);
#pragma unroll
      for (int r = 0; r < 4; ++r) {
        uint hv = h1(leaky(acc[r] + bias_l[i]));
        uint pv = dpp_xor1_u(hv);
        if (!(l & 1))
          f0h32[(size_t)(tile * 16 + q * 4 + r) * 64 + nt * 8 + (n16 >> 1)] =
              hv | (pv << 16);
      }
    }
  }
}

// ---------------- mlp1 (MFMA): value = leaky(f0@w1^T+b1) @ ow^T + ob --------
__global__ __launch_bounds__(256) void mlp1(const uint* __restrict__ f0h,
                                            const float* __restrict__ w1,
                                            const float* __restrict__ b1,
                                            const float* __restrict__ ow,
                                            const float* __restrict__ obp,
                                            float* __restrict__ value) {
  const int tid = threadIdx.x;
  const int l = tid & 63, wv = tid >> 6;
  const int n16 = l & 15, q = l >> 4;

  f16x8 Bf[8][4];
  float bias_l[8], ow_l[8];
#pragma unroll
  for (int nt = 0; nt < 8; ++nt) {
    const int n = nt * 16 + n16;
    const float* wrow = w1 + (size_t)n * 128;
#pragma unroll
    for (int f = 0; f < 4; ++f) Bf[nt][f] = ldw8(wrow + f * 32 + q * 8);
    bias_l[nt] = b1[n];
    ow_l[nt] = ow[n];
  }
  const float obias = obp[0];

  for (int tile = blockIdx.x * 4 + wv; tile < NT / 16; tile += gridDim.x * 4) {
    const uint4* arow = (const uint4*)(f0h + (size_t)(tile * 16 + n16) * 64);
    f16x8 A[4];
#pragma unroll
    for (int f = 0; f < 4; ++f) A[f] = __builtin_bit_cast(f16x8, arow[f * 4 + q]);
    float s0 = 0.f, s1 = 0.f, s2 = 0.f, s3 = 0.f;
#pragma unroll
    for (int nt = 0; nt < 8; ++nt) {
      f32x4 acc = {0.f, 0.f, 0.f, 0.f};
#pragma unroll
      for (int f = 0; f < 4; ++f)
        acc = __builtin_amdgcn_mfma_f32_16x16x32_f16(A[f], Bf[nt][f], acc, 0, 0, 0);
      s0 += leaky(acc[0] + bias_l[nt]) * ow_l[nt];
      s1 += leaky(acc[1] + bias_l[nt]) * ow_l[nt];
      s2 += leaky(acc[2] + bias_l[nt]) * ow_l[nt];
      s3 += leaky(acc[3] + bias_l[nt]) * ow_l[nt];
    }
#pragma unroll
    for (int mask = 1; mask < 16; mask <<= 1) {
      s0 += shflx(s0, mask);
      s1 += shflx(s1, mask);
      s2 += shflx(s2, mask);
      s3 += shflx(s3, mask);
    }
    if (n16 == 0) {
      value[tile * 16 + q * 4 + 0] = s0 + obias;
      value[tile * 16 + q * 4 + 1] = s1 + obias;
      value[tile * 16 + q * 4 + 2] = s2 + obias;
      value[tile * 16 + q * 4 + 3] = s3 + obias;
    }
  }
}

__global__ void fill_sentinel(float* o, int n) {
  for (int i = blockIdx.x * blockDim.x + threadIdx.x; i < n; i += gridDim.x * blockDim.x)
    o[i] = 999.0f;
}

extern "C" void kernel_launch(void* const* d_in, const int* in_sizes, int n_in,
                              void* d_out, int out_size, void* d_ws, size_t ws_size,
                              hipStream_t stream) {
  const float* obs = (const float*)d_in[0];
  const float* hs = (const float*)d_in[1];
  const float* me_w1 = (const float*)d_in[2];
  const float* me_b1 = (const float*)d_in[3];
  const float* me_w2 = (const float*)d_in[4];
  const float* me_b2 = (const float*)d_in[5];
  const float* ae_w1 = (const float*)d_in[6];
  const float* ae_b1 = (const float*)d_in[7];
  const float* ae_w2 = (const float*)d_in[8];
  const float* ae_b2 = (const float*)d_in[9];
  const float* ipw = (const float*)d_in[10];
  const float* ipb = (const float*)d_in[11];
  const float* opw = (const float*)d_in[12];
  const float* opb = (const float*)d_in[13];
  const float* lng = (const float*)d_in[14];
  const float* lnb = (const float*)d_in[15];
  const float* wih = (const float*)d_in[16];
  const float* whh = (const float*)d_in[17];
  const float* bih = (const float*)d_in[18];
  const float* bhh = (const float*)d_in[19];
  const float* w0 = (const float*)d_in[20];
  const float* b0 = (const float*)d_in[21];
  const float* w1 = (const float*)d_in[22];
  const float* b1 = (const float*)d_in[23];
  const float* ow = (const float*)d_in[24];
  const float* ob = (const float*)d_in[25];

  // workspace (128 MiB):
  //  region A [0, 100.66MB): xp bf16 [NT,384]; later f0h f16 [NT,128]
  //  region B [100.66MB, 134.22MB): xnh f16-pairs [NT,32]; later gouth f16 [NT,128]
  const size_t regA_bytes = (size_t)NT * G3 * sizeof(bf16);
  const size_t regB_bytes = (size_t)NT * 64 * sizeof(uint);
  const size_t need = regA_bytes + regB_bytes;  // 134,217,728
  float* out = (float*)d_out;
  if (ws_size < need) {
    fill_sentinel<<<288, 256, 0, stream>>>(out, out_size);
    return;
  }

  char* ws = (char*)d_ws;
  bf16* xp = (bf16*)ws;
  uint* f0h = (uint*)ws;
  uint* xnh = (uint*)(ws + regA_bytes);
  ushort* gouth = (ushort*)(ws + regA_bytes);

  pre_a<<<1024, 256, 0, stream>>>(obs, me_w1, me_b1, me_w2, me_b2, ae_w1, ae_b1,
                                  ae_w2, ae_b2, ipw, ipb, opw, opb, lng, lnb, xnh);
  pre_b<<<1024, 256, 0, stream>>>(xnh, wih, bih, (uint*)xp);
  gru_kernel<<<BB, 576, 0, stream>>>(xp, hs, whh, bhh, gouth, out + NT);
  mlp0<<<1024, 256, 0, stream>>>((const uint*)gouth, w0, b0, f0h);
  mlp1<<<1024, 256, 0, stream>>>(f0h, w1, b1, ow, ob, out);
}

// Round 14
// 787.278 us; speedup vs baseline: 1.1847x; 1.1847x over previous
//
#include <hip/hip_runtime.h>
#include <hip/hip_bf16.h>

#define BB 128
#define SS 1024
#define HH 128
#define G3 384
#define NT (BB * SS)   // 131072 tokens

typedef __hip_bfloat16 bf16;
typedef unsigned int uint;
typedef unsigned short ushort;
typedef _Float16 f16;
typedef f16 f16x2 __attribute__((ext_vector_type(2)));
typedef f16 f16x8 __attribute__((ext_vector_type(8)));
typedef float f32x4 __attribute__((ext_vector_type(4)));

__device__ __forceinline__ float leaky(float x) { return x >= 0.f ? x : 0.01f * x; }
__device__ __forceinline__ f16x2 u2h(uint u) { return __builtin_bit_cast(f16x2, u); }
__device__ __forceinline__ uint packh2(float a, float b) {
  f16x2 h; h.x = (f16)a; h.y = (f16)b;
  return __builtin_bit_cast(uint, h);
}
__device__ __forceinline__ uint h1(float a) {
  return (uint)__builtin_bit_cast(ushort, (f16)a);
}
__device__ __forceinline__ uint bf_rne(float f) {
  uint u = __float_as_uint(f);
  return (u + 0x7FFFu + ((u >> 16) & 1u)) >> 16;
}
__device__ __forceinline__ float shflx(float v, int m) { return __shfl_xor(v, m, 64); }
__device__ __forceinline__ uint dpp_xor1_u(uint v) {
  int i = __builtin_amdgcn_update_dpp(0, (int)v, 0xB1, 0xF, 0xF, true);
  return (uint)i;
}
#define WSYNC() asm volatile("s_waitcnt lgkmcnt(0)" ::: "memory")

template <int NP>
__device__ __forceinline__ void ldrow(const float* __restrict__ p, f16x2* w) {
#pragma unroll
  for (int i = 0; i < NP; ++i) {
    f16x2 h; h.x = (f16)p[2 * i]; h.y = (f16)p[2 * i + 1];
    w[i] = h;
  }
}
__device__ __forceinline__ f16x8 ldw8(const float* __restrict__ p) {
  f16x8 v;
#pragma unroll
  for (int j = 0; j < 8; ++j) v[j] = (f16)p[j];
  return v;
}
template <int NP>
__device__ __forceinline__ float dot2l(const uint* __restrict__ x,
                                       const f16x2* __restrict__ w, float acc) {
#pragma unroll
  for (int i = 0; i < NP / 4; ++i) {
    uint4 uu = ((const uint4*)x)[i];
    acc = __builtin_amdgcn_fdot2(u2h(uu.x), w[4 * i + 0], acc, false);
    acc = __builtin_amdgcn_fdot2(u2h(uu.y), w[4 * i + 1], acc, false);
    acc = __builtin_amdgcn_fdot2(u2h(uu.z), w[4 * i + 2], acc, false);
    acc = __builtin_amdgcn_fdot2(u2h(uu.w), w[4 * i + 3], acc, false);
  }
  return acc;
}
__device__ __forceinline__ float d4(uint4 x, uint4 w, float acc) {
  acc = __builtin_amdgcn_fdot2(u2h(x.x), u2h(w.x), acc, false);
  acc = __builtin_amdgcn_fdot2(u2h(x.y), u2h(w.y), acc, false);
  acc = __builtin_amdgcn_fdot2(u2h(x.z), u2h(w.z), acc, false);
  acc = __builtin_amdgcn_fdot2(u2h(x.w), u2h(w.w), acc, false);
  return acc;
}

// ---------------- pre_a: encoders + attention + LN -> xnh (f16 pairs) -------
__global__ __launch_bounds__(256, 4) void pre_a(
    const float* __restrict__ obs, const float* __restrict__ me_w1,
    const float* __restrict__ me_b1, const float* __restrict__ me_w2,
    const float* __restrict__ me_b2, const float* __restrict__ ae_w1,
    const float* __restrict__ ae_b1, const float* __restrict__ ae_w2,
    const float* __restrict__ ae_b2, const float* __restrict__ ipw,
    const float* __restrict__ ipb, const float* __restrict__ opw,
    const float* __restrict__ opb, const float* __restrict__ lng,
    const float* __restrict__ lnb, uint* __restrict__ xnh) {
  __shared__ float ss[352];
  __shared__ __align__(16) uint4 w4[8 * 256];  // 32 KB: [chunk c][row r]
  __shared__ __align__(16) uint ex[4][176];

  const int tid = threadIdx.x;
  const int wid = tid >> 6, l = tid & 63;
  if (tid < 96) ss[tid] = me_w1[tid];
  if (tid < 32) ss[96 + tid] = me_b1[tid];
  if (tid < 192) ss[128 + tid] = ae_w1[tid];
  if (tid < 32) ss[320 + tid] = ae_b1[tid];

  for (int idx = tid; idx < 2048; idx += 256) {
    const int r = idx & 255, c = idx >> 8;
    const float* src =
        (r < 192 ? ipw + (size_t)r * 64 : opw + (size_t)(r - 192) * 64) + c * 8;
    uint4 u;
    u.x = packh2(src[0], src[1]);
    u.y = packh2(src[2], src[3]);
    u.z = packh2(src[4], src[5]);
    u.w = packh2(src[6], src[7]);
    w4[(c << 8) + r] = u;
  }

  f16x2 wme2[16], wae2[16];
  ldrow<16>(me_w2 + l * 32, wme2);
  ldrow<16>(ae_w2 + l * 32, wae2);
  const float bme2 = me_b2[l], bae2 = ae_b2[l];
  const float bq = ipb[l], bk = ipb[64 + l], bv = ipb[128 + l], bop = opb[l];
  const float gl = lng[l], bl = lnb[l];
  __syncthreads();

  uint* um = ex[wid];
  uint* ua = um + 32;
  uint* e1 = um + 48;
  uint* e2 = um + 80;
  uint* ea = um + 112;
  uint* ec = um + 144;

  for (int base = blockIdx.x * 4; base < NT; base += 4096) {
    const size_t token = base + wid;
    const float4* ob4 = (const float4*)(obs + token * 12);
    float4 o0 = ob4[0], o1 = ob4[1], o2 = ob4[2];

    const int row = l & 31;
    const bool m2h = l >= 32;
    float i0 = m2h ? o0.w : o0.x, i1 = m2h ? o1.x : o0.y, i2 = m2h ? o1.y : o0.z;
    float t1 = ss[96 + row] + i0 * ss[row * 3] + i1 * ss[row * 3 + 1] + i2 * ss[row * 3 + 2];
    t1 = leaky(t1);
    float ta = ss[320 + row] + o1.z * ss[128 + row * 6] + o1.w * ss[128 + row * 6 + 1] +
               o2.x * ss[128 + row * 6 + 2] + o2.y * ss[128 + row * 6 + 3] +
               o2.z * ss[128 + row * 6 + 4] + o2.w * ss[128 + row * 6 + 5];
    ta = leaky(ta);
    float t1p = shflx(t1, 1), tap = shflx(ta, 1);
    if (!(l & 1)) {
      um[l >> 1] = packh2(t1, t1p);
      if (l < 32) ua[l >> 1] = packh2(ta, tap);
    }
    WSYNC();

    float m1e = dot2l<16>(um, wme2, bme2);
    float m2e = dot2l<16>(um + 16, wme2, bme2);
    float ace = dot2l<16>(ua, wae2, bae2);
    float m1p = shflx(m1e, 1), m2p = shflx(m2e, 1), acp = shflx(ace, 1);
    if (!(l & 1)) {
      e1[l >> 1] = packh2(m1e, m1p);
      e2[l >> 1] = packh2(m2e, m2p);
      ea[l >> 1] = packh2(ace, acp);
    }
    WSYNC();

    float q = bq, k1 = bk, k2 = bk, v1 = bv, v2 = bv;
    {
      const uint4* xe1 = (const uint4*)e1;
      const uint4* xe2 = (const uint4*)e2;
      const uint4* xea = (const uint4*)ea;
#pragma unroll
      for (int c = 0; c < 8; ++c) {
        uint4 x1 = xe1[c], x2 = xe2[c], xa = xea[c];
        uint4 uq = w4[(c << 8) + l];
        uint4 uk = w4[(c << 8) + 64 + l];
        uint4 uv = w4[(c << 8) + 128 + l];
        q = d4(xa, uq, q);
        k1 = d4(x1, uk, k1);
        k2 = d4(x2, uk, k2);
        v1 = d4(x1, uv, v1);
        v2 = d4(x2, uv, v2);
      }
    }

    float p1 = q * k1, p2 = q * k2;
    p1 += shflx(p1, 1); p2 += shflx(p2, 1);
    p1 += shflx(p1, 2); p2 += shflx(p2, 2);
    p1 += shflx(p1, 4); p2 += shflx(p2, 4);
    p1 += shflx(p1, 8); p2 += shflx(p2, 8);
    float s1 = p1 * 0.25f, s2 = p2 * 0.25f;
    float mx = fmaxf(s1, s2);
    float ev1 = __expf(s1 - mx), ev2 = __expf(s2 - mx);
    float a1 = ev1 / (ev1 + ev2);
    float ctx = a1 * v1 + (1.f - a1) * v2;
    float cxp = shflx(ctx, 1);
    if (!(l & 1)) ec[l >> 1] = packh2(ctx, cxp);
    WSYNC();

    float ao = bop;
    {
      const uint4* xec = (const uint4*)ec;
#pragma unroll
      for (int c = 0; c < 8; ++c) {
        ao = d4(xec[c], w4[(c << 8) + 192 + l], ao);
      }
    }
    float x = ao + ace;
    float s = x, s2s = x * x;
#pragma unroll
    for (int off = 32; off; off >>= 1) {
      s += shflx(s, off);
      s2s += shflx(s2s, off);
    }
    float mu = s * (1.f / 64.f);
    float var = s2s * (1.f / 64.f) - mu * mu;
    float rs = rsqrtf(var + 1e-5f);
    float xn = (x - mu) * rs * gl + bl;
    float xnp = shflx(xn, 1);
    if (!(l & 1)) xnh[token * 32 + (l >> 1)] = packh2(xn, xnp);
  }
}

// ---------------- pre_b (MFMA): xp[NT,384] = xn[NT,64] @ W_ih^T + b ---------
__global__ __launch_bounds__(256) void pre_b(const uint* __restrict__ xnh,
                                             const float* __restrict__ wih,
                                             const float* __restrict__ bih,
                                             uint* __restrict__ xp32) {
  const int tid = threadIdx.x;
  const int l = tid & 63, wv = tid >> 6;
  const int n16 = l & 15, q = l >> 4;

  f16x8 Bf[6][2];
  float bias_l[6];
#pragma unroll
  for (int i = 0; i < 6; ++i) {
    const int n = (wv * 6 + i) * 16 + n16;
    const float* wrow = wih + (size_t)n * 64;
    Bf[i][0] = ldw8(wrow + q * 8);
    Bf[i][1] = ldw8(wrow + 32 + q * 8);
    bias_l[i] = bih[n];
  }

  for (int tile = blockIdx.x; tile < NT / 16; tile += gridDim.x) {
    const uint4* arow = (const uint4*)(xnh + (size_t)(tile * 16 + n16) * 32);
    f16x8 A0 = __builtin_bit_cast(f16x8, arow[q]);
    f16x8 A1 = __builtin_bit_cast(f16x8, arow[4 + q]);
#pragma unroll
    for (int i = 0; i < 6; ++i) {
      const int nt = wv * 6 + i;
      f32x4 acc = {0.f, 0.f, 0.f, 0.f};
      acc = __builtin_amdgcn_mfma_f32_16x16x32_f16(A0, Bf[i][0], acc, 0, 0, 0);
      acc = __builtin_amdgcn_mfma_f32_16x16x32_f16(A1, Bf[i][1], acc, 0, 0, 0);
#pragma unroll
      for (int r = 0; r < 4; ++r) {
        uint bv = bf_rne(acc[r] + bias_l[i]);
        uint pv = dpp_xor1_u(bv);
        if (!(l & 1))
          xp32[(size_t)(tile * 16 + q * 4 + r) * 192 + nt * 8 + (n16 >> 1)] =
              bv | (pv << 16);
      }
    }
  }
}

// ---------------- gru (MFMA matvec): 4 compute waves + 1 producer -----------
// Per step, wave w computes n-tiles {2w,2w+1, 8+2w,9+2w, 16+2w,17+2w} of
// P = h @ W_hh^T via 24 mfma_16x16x32_f16. All A rows are identical (each
// quad broadcasts its h k-chunk), so every lane's acc holds P[col] -> no
// C-layout transpose. Quads 0/1 gate n1=32w+c, quads 2/3 gate n2=32w+16+c;
// quads 0,2 publish to f16 h double-buffer + gout. One lgkm barrier/step.
__global__ __launch_bounds__(320, 1) void gru_kernel(
    const bf16* __restrict__ xp, const float* __restrict__ hs,
    const float* __restrict__ whh, const float* __restrict__ bhh,
    ushort* __restrict__ gouth, float* __restrict__ hlast) {
  __shared__ __align__(16) ushort hbuf[2][HH];
  __shared__ __align__(16) uint ring[8 * 192];
  const int tid = threadIdx.x;
  const int b = blockIdx.x;
  const bool comp = tid < 256;
  const int lane = tid & 63;
  const int w = tid >> 6;          // 0..3 compute, 4 producer
  const int n16 = lane & 15, q = lane >> 4;
  const int pid = tid - 256;

  f16x8 Bf[6][4];
  float bias_r = 0.f, bias_z = 0.f, bias_g = 0.f, hp = 0.f;
  int idx = 0;
  const uint* xr32 = (const uint*)(xp + (size_t)b * SS * G3);
  uint a0 = 0, a1 = 0, a2 = 0, c0 = 0, c1 = 0, c2 = 0;
  if (comp) {
    // tile i -> n-tile index
    const int tn[6] = {2 * w, 2 * w + 1, 8 + 2 * w, 9 + 2 * w, 16 + 2 * w, 17 + 2 * w};
#pragma unroll
    for (int i = 0; i < 6; ++i) {
      const float* wrow = whh + (size_t)(tn[i] * 16 + n16) * HH;
#pragma unroll
      for (int kt = 0; kt < 4; ++kt) Bf[i][kt] = ldw8(wrow + kt * 32 + q * 8);
    }
    idx = 32 * w + n16 + ((q >> 1) ? 16 : 0);  // quads 0/1 -> n1, 2/3 -> n2
    bias_r = bhh[idx];
    bias_z = bhh[HH + idx];
    bias_g = bhh[2 * HH + idx];
    hp = hs[b * HH + idx];
    if (tid < HH) hbuf[0][tid] = (ushort)h1(hs[b * HH + tid]);
  } else {
    for (int s = 0; s < 4; ++s) {
      const uint* p = xr32 + s * 192 + pid * 3;
      uint v0 = p[0], v1 = p[1], v2 = p[2];
      uint* qq = ring + s * 192 + pid * 3;
      qq[0] = v0; qq[1] = v1; qq[2] = v2;
    }
    const uint* pa = xr32 + 4 * 192 + pid * 3;
    a0 = pa[0]; a1 = pa[1]; a2 = pa[2];
    const uint* pb = xr32 + 5 * 192 + pid * 3;
    c0 = pb[0]; c1 = pb[1]; c2 = pb[2];
  }
  __syncthreads();

  const ushort* ring_us = (const ushort*)ring;
  ushort* grow = gouth + (size_t)b * SS * HH;
  const bool pub = comp && !(q & 1);  // quads 0 and 2
  const int sel = q >> 1;             // 0: use tiles {0,2,4}; 1: {1,3,5}

#define CSTEP(TT, RD, WRI)                                                     \
  {                                                                            \
    const int slot = (TT) & 7;                                                 \
    const uint4* hb = (const uint4*)hbuf[RD];                                  \
    f16x8 A0 = __builtin_bit_cast(f16x8, hb[q]);                               \
    f16x8 A1 = __builtin_bit_cast(f16x8, hb[4 + q]);                           \
    f16x8 A2 = __builtin_bit_cast(f16x8, hb[8 + q]);                           \
    f16x8 A3 = __builtin_bit_cast(f16x8, hb[12 + q]);                          \
    f32x4 ac0 = {0.f, 0.f, 0.f, 0.f}, ac1 = ac0, ac2 = ac0, ac3 = ac0,         \
          ac4 = ac0, ac5 = ac0;                                                \
    ac0 = __builtin_amdgcn_mfma_f32_16x16x32_f16(A0, Bf[0][0], ac0, 0, 0, 0);  \
    ac1 = __builtin_amdgcn_mfma_f32_16x16x32_f16(A0, Bf[1][0], ac1, 0, 0, 0);  \
    ac2 = __builtin_amdgcn_mfma_f32_16x16x32_f16(A0, Bf[2][0], ac2, 0, 0, 0);  \
    ac3 = __builtin_amdgcn_mfma_f32_16x16x32_f16(A0, Bf[3][0], ac3, 0, 0, 0);  \
    ac4 = __builtin_amdgcn_mfma_f32_16x16x32_f16(A0, Bf[4][0], ac4, 0, 0, 0);  \
    ac5 = __builtin_amdgcn_mfma_f32_16x16x32_f16(A0, Bf[5][0], ac5, 0, 0, 0);  \
    ac0 = __builtin_amdgcn_mfma_f32_16x16x32_f16(A1, Bf[0][1], ac0, 0, 0, 0);  \
    ac1 = __builtin_amdgcn_mfma_f32_16x16x32_f16(A1, Bf[1][1], ac1, 0, 0, 0);  \
    ac2 = __builtin_amdgcn_mfma_f32_16x16x32_f16(A1, Bf[2][1], ac2, 0, 0, 0);  \
    ac3 = __builtin_amdgcn_mfma_f32_16x16x32_f16(A1, Bf[3][1], ac3, 0, 0, 0);  \
    ac4 = __builtin_amdgcn_mfma_f32_16x16x32_f16(A1, Bf[4][1], ac4, 0, 0, 0);  \
    ac5 = __builtin_amdgcn_mfma_f32_16x16x32_f16(A1, Bf[5][1], ac5, 0, 0, 0);  \
    ac0 = __builtin_amdgcn_mfma_f32_16x16x32_f16(A2, Bf[0][2], ac0, 0, 0, 0);  \
    ac1 = __builtin_amdgcn_mfma_f32_16x16x32_f16(A2, Bf[1][2], ac1, 0, 0, 0);  \
    ac2 = __builtin_amdgcn_mfma_f32_16x16x32_f16(A2, Bf[2][2], ac2, 0, 0, 0);  \
    ac3 = __builtin_amdgcn_mfma_f32_16x16x32_f16(A2, Bf[3][2], ac3, 0, 0, 0);  \
    ac4 = __builtin_amdgcn_mfma_f32_16x16x32_f16(A2, Bf[4][2], ac4, 0, 0, 0);  \
    ac5 = __builtin_amdgcn_mfma_f32_16x16x32_f16(A2, Bf[5][2], ac5, 0, 0, 0);  \
    ac0 = __builtin_amdgcn_mfma_f32_16x16x32_f16(A3, Bf[0][3], ac0, 0, 0, 0);  \
    ac1 = __builtin_amdgcn_mfma_f32_16x16x32_f16(A3, Bf[1][3], ac1, 0, 0, 0);  \
    ac2 = __builtin_amdgcn_mfma_f32_16x16x32_f16(A3, Bf[2][3], ac2, 0, 0, 0);  \
    ac3 = __builtin_amdgcn_mfma_f32_16x16x32_f16(A3, Bf[3][3], ac3, 0, 0, 0);  \
    ac4 = __builtin_amdgcn_mfma_f32_16x16x32_f16(A3, Bf[4][3], ac4, 0, 0, 0);  \
    ac5 = __builtin_amdgcn_mfma_f32_16x16x32_f16(A3, Bf[5][3], ac5, 0, 0, 0);  \
    float Pr = (sel ? ac1[0] : ac0[0]) + bias_r;                               \
    float Pz = (sel ? ac3[0] : ac2[0]) + bias_z;                               \
    float Pg = (sel ? ac5[0] : ac4[0]) + bias_g;                               \
    uint bxr = ring_us[slot * 384 + idx];                                      \
    uint bxz = ring_us[slot * 384 + 128 + idx];                                \
    uint bxg = ring_us[slot * 384 + 256 + idx];                                \
    float r = 1.f / (1.f + __expf(-(__uint_as_float(bxr << 16) + Pr)));        \
    float z = 1.f / (1.f + __expf(-(__uint_as_float(bxz << 16) + Pz)));        \
    float gp = __uint_as_float(bxg << 16) + r * Pg;                            \
    float e = __expf(-2.f * fabsf(gp));                                        \
    float th = copysignf((1.f - e) / (1.f + e), gp);                           \
    float hn = (1.f - z) * th + z * hp;                                        \
    hp = hn;                                                                   \
    if (pub) {                                                                 \
      ushort hb16 = (ushort)h1(hn);                                            \
      hbuf[WRI][idx] = hb16;                                                   \
      grow[(size_t)(TT)*HH + idx] = hb16;                                      \
    }                                                                          \
  }

#define PSTEP(TT, R0, R1, R2)                                                  \
  {                                                                            \
    const int wrow = (TT) + 4;                                                 \
    if (wrow < SS) {                                                           \
      uint* qq = ring + (wrow & 7) * 192 + pid * 3;                            \
      qq[0] = R0; qq[1] = R1; qq[2] = R2;                                      \
      const int lrow = (TT) + 6;                                               \
      if (lrow < SS) {                                                         \
        const uint* p = xr32 + lrow * 192 + pid * 3;                           \
        R0 = p[0]; R1 = p[1]; R2 = p[2];                                       \
      }                                                                        \
    }                                                                          \
  }

  for (int t = 0; t < SS; t += 2) {
    if (comp) {
      CSTEP(t, 0, 1);
    } else {
      PSTEP(t, a0, a1, a2);
    }
    asm volatile("s_waitcnt lgkmcnt(0)\n\ts_barrier" ::: "memory");
    if (comp) {
      CSTEP(t + 1, 1, 0);
    } else {
      PSTEP(t + 1, c0, c1, c2);
    }
    asm volatile("s_waitcnt lgkmcnt(0)\n\ts_barrier" ::: "memory");
  }
#undef CSTEP
#undef PSTEP
  if (pub) hlast[b * HH + idx] = hp;
}

// ---------------- mlp0 (MFMA): f0[NT,128] = leaky(g @ w0^T + b0) ------------
__global__ __launch_bounds__(256) void mlp0(const uint* __restrict__ gh,
                                            const float* __restrict__ w0,
                                            const float* __restrict__ b0,
                                            uint* __restrict__ f0h32) {
  const int tid = threadIdx.x;
  const int l = tid & 63, wv = tid >> 6;
  const int n16 = l & 15, q = l >> 4;

  f16x8 Bf[2][4];
  float bias_l[2];
#pragma unroll
  for (int i = 0; i < 2; ++i) {
    const int n = (wv * 2 + i) * 16 + n16;
    const float* wrow = w0 + (size_t)n * 128;
#pragma unroll
    for (int f = 0; f < 4; ++f) Bf[i][f] = ldw8(wrow + f * 32 + q * 8);
    bias_l[i] = b0[n];
  }

  for (int tile = blockIdx.x; tile < NT / 16; tile += gridDim.x) {
    const uint4* arow = (const uint4*)(gh + (size_t)(tile * 16 + n16) * 64);
    f16x8 A[4];
#pragma unroll
    for (int f = 0; f < 4; ++f) A[f] = __builtin_bit_cast(f16x8, arow[f * 4 + q]);
#pragma unroll
    for (int i = 0; i < 2; ++i) {
      const int nt = wv * 2 + i;
      f32x4 acc = {0.f, 0.f, 0.f, 0.f};
#pragma unroll
      for (int f = 0; f < 4; ++f)
        acc = __builtin_amdgcn_mfma_f32_16x16x32_f16(A[f], Bf[i][f], acc, 0, 0, 0);
#pragma unroll
      for (int r = 0; r < 4; ++r) {
        uint hv = h1(leaky(acc[r] + bias_l[i]));
        uint pv = dpp_xor1_u(hv);
        if (!(l & 1))
          f0h32[(size_t)(tile * 16 + q * 4 + r) * 64 + nt * 8 + (n16 >> 1)] =
              hv | (pv << 16);
      }
    }
  }
}

// ---------------- mlp1 (MFMA): value = leaky(f0@w1^T+b1) @ ow^T + ob --------
__global__ __launch_bounds__(256) void mlp1(const uint* __restrict__ f0h,
                                            const float* __restrict__ w1,
                                            const float* __restrict__ b1,
                                            const float* __restrict__ ow,
                                            const float* __restrict__ obp,
                                            float* __restrict__ value) {
  const int tid = threadIdx.x;
  const int l = tid & 63, wv = tid >> 6;
  const int n16 = l & 15, q = l >> 4;

  f16x8 Bf[8][4];
  float bias_l[8], ow_l[8];
#pragma unroll
  for (int nt = 0; nt < 8; ++nt) {
    const int n = nt * 16 + n16;
    const float* wrow = w1 + (size_t)n * 128;
#pragma unroll
    for (int f = 0; f < 4; ++f) Bf[nt][f] = ldw8(wrow + f * 32 + q * 8);
    bias_l[nt] = b1[n];
    ow_l[nt] = ow[n];
  }
  const float obias = obp[0];

  for (int tile = blockIdx.x * 4 + wv; tile < NT / 16; tile += gridDim.x * 4) {
    const uint4* arow = (const uint4*)(f0h + (size_t)(tile * 16 + n16) * 64);
    f16x8 A[4];
#pragma unroll
    for (int f = 0; f < 4; ++f) A[f] = __builtin_bit_cast(f16x8, arow[f * 4 + q]);
    float s0 = 0.f, s1 = 0.f, s2 = 0.f, s3 = 0.f;
#pragma unroll
    for (int nt = 0; nt < 8; ++nt) {
      f32x4 acc = {0.f, 0.f, 0.f, 0.f};
#pragma unroll
      for (int f = 0; f < 4; ++f)
        acc = __builtin_amdgcn_mfma_f32_16x16x32_f16(A[f], Bf[nt][f], acc, 0, 0, 0);
      s0 += leaky(acc[0] + bias_l[nt]) * ow_l[nt];
      s1 += leaky(acc[1] + bias_l[nt]) * ow_l[nt];
      s2 += leaky(acc[2] + bias_l[nt]) * ow_l[nt];
      s3 += leaky(acc[3] + bias_l[nt]) * ow_l[nt];
    }
#pragma unroll
    for (int mask = 1; mask < 16; mask <<= 1) {
      s0 += shflx(s0, mask);
      s1 += shflx(s1, mask);
      s2 += shflx(s2, mask);
      s3 += shflx(s3, mask);
    }
    if (n16 == 0) {
      value[tile * 16 + q * 4 + 0] = s0 + obias;
      value[tile * 16 + q * 4 + 1] = s1 + obias;
      value[tile * 16 + q * 4 + 2] = s2 + obias;
      value[tile * 16 + q * 4 + 3] = s3 + obias;
    }
  }
}

__global__ void fill_sentinel(float* o, int n) {
  for (int i = blockIdx.x * blockDim.x + threadIdx.x; i < n; i += gridDim.x * blockDim.x)
    o[i] = 999.0f;
}

extern "C" void kernel_launch(void* const* d_in, const int* in_sizes, int n_in,
                              void* d_out, int out_size, void* d_ws, size_t ws_size,
                              hipStream_t stream) {
  const float* obs = (const float*)d_in[0];
  const float* hs = (const float*)d_in[1];
  const float* me_w1 = (const float*)d_in[2];
  const float* me_b1 = (const float*)d_in[3];
  const float* me_w2 = (const float*)d_in[4];
  const float* me_b2 = (const float*)d_in[5];
  const float* ae_w1 = (const float*)d_in[6];
  const float* ae_b1 = (const float*)d_in[7];
  const float* ae_w2 = (const float*)d_in[8];
  const float* ae_b2 = (const float*)d_in[9];
  const float* ipw = (const float*)d_in[10];
  const float* ipb = (const float*)d_in[11];
  const float* opw = (const float*)d_in[12];
  const float* opb = (const float*)d_in[13];
  const float* lng = (const float*)d_in[14];
  const float* lnb = (const float*)d_in[15];
  const float* wih = (const float*)d_in[16];
  const float* whh = (const float*)d_in[17];
  const float* bih = (const float*)d_in[18];
  const float* bhh = (const float*)d_in[19];
  const float* w0 = (const float*)d_in[20];
  const float* b0 = (const float*)d_in[21];
  const float* w1 = (const float*)d_in[22];
  const float* b1 = (const float*)d_in[23];
  const float* ow = (const float*)d_in[24];
  const float* ob = (const float*)d_in[25];

  // workspace (128 MiB):
  //  region A [0, 100.66MB): xp bf16 [NT,384]; later f0h f16 [NT,128]
  //  region B [100.66MB, 134.22MB): xnh f16-pairs [NT,32]; later gouth f16 [NT,128]
  const size_t regA_bytes = (size_t)NT * G3 * sizeof(bf16);
  const size_t regB_bytes = (size_t)NT * 64 * sizeof(uint);
  const size_t need = regA_bytes + regB_bytes;  // 134,217,728
  float* out = (float*)d_out;
  if (ws_size < need) {
    fill_sentinel<<<288, 256, 0, stream>>>(out, out_size);
    return;
  }

  char* ws = (char*)d_ws;
  bf16* xp = (bf16*)ws;
  uint* f0h = (uint*)ws;
  uint* xnh = (uint*)(ws + regA_bytes);
  ushort* gouth = (ushort*)(ws + regA_bytes);

  pre_a<<<1024, 256, 0, stream>>>(obs, me_w1, me_b1, me_w2, me_b2, ae_w1, ae_b1,
                                  ae_w2, ae_b2, ipw, ipb, opw, opb, lng, lnb, xnh);
  pre_b<<<1024, 256, 0, stream>>>(xnh, wih, bih, (uint*)xp);
  gru_kernel<<<BB, 320, 0, stream>>>(xp, hs, whh, bhh, gouth, out + NT);
  mlp0<<<1024, 256, 0, stream>>>((const uint*)gouth, w0, b0, f0h);
  mlp1<<<1024, 256, 0, stream>>>(f0h, w1, b1, ow, ob, out);
}